// Round 11
// baseline (105.671 us; speedup 1.0000x reference)
//
#include <hip/hip_runtime.h>

typedef unsigned long long u64;
typedef unsigned u32;

#define BATCH 16
#define Hh 512
#define Ww 512
#define IMG (Hh * Ww)          // 262144
#define TOT (BATCH * IMG)      // 4194304
#define WPI (IMG / 64)         // 4096 words per image
#define WROW 8                 // words per row
#define NWORDS (TOT / 64)      // 65536
#define MIN_SIZE 262           // keep strictly greater
#define GHASH 131072           // global root->size hash (power of 2, load ~0.3)
#define LHASH 2048             // per-block hash in count

#define BAND 8
#define HALO 4
#define BROWS (BAND + 2 * HALO)     // 16
#define BWORDS (BROWS * WROW)       // 128
#define NODES (BAND * Ww)           // 4096 nodes per band

// run start within a 64-bit word: nearest zero at-or-below bit s, +1.
__device__ __forceinline__ u32 runstart(u64 bits, int s) {
    u64 ms = (s >= 63) ? ~0ULL : ((1ULL << (s + 1)) - 1);
    u64 nz = ~bits & ms;
    return nz ? (u32)(64 - __clzll(nz)) : 0u;
}
// run length starting at set bit s (within word)
__device__ __forceinline__ u32 runlen(u64 bits, int s) {
    u64 v = ~(bits >> s);
    return v ? (u32)(__ffsll(v) - 1) : (u32)(64 - s);
}

__device__ __forceinline__ u64 morph_word(const u64* M, int w, int rr, bool er) {
    const u64 B = er ? ~0ULL : 0ULL;
    int wx = w & 7;
    u64 cc = M[w];
    u64 lf = (cc << 1) | (wx > 0 ? (M[w - 1] >> 63) : (er ? 1ULL : 0ULL));
    u64 rt = (cc >> 1) | (wx < 7 ? (M[w + 1] << 63) : (er ? (1ULL << 63) : 0ULL));
    u64 up = (rr <= 0)      ? B : (w >= WROW          ? M[w - WROW] : B);
    u64 dn = (rr >= Hh - 1) ? B : (w < BWORDS - WROW  ? M[w + WROW] : B);
    return er ? (cc & lf & rt & up & dn) : (cc | lf | rt | up | dn);
}

// ---------------- union-find primitives (LDS or global) ----------------
template <typename P>
__device__ __forceinline__ u32 uf_find_halve(P L, u32 x) {
    while (true) {
        u32 p = L[x];
        if (p == x) return x;
        u32 gp = L[p];
        if (gp == p) return p;
        atomicMin(&L[x], gp);   // halving: gp <= p < x, monotone-safe
        x = gp;
    }
}
template <typename P>
__device__ __forceinline__ void uf_merge(P L, u32 a, u32 b) {
    while (true) {
        a = uf_find_halve(L, a);
        b = uf_find_halve(L, b);
        if (a == b) return;
        if (a > b) { u32 t = a; a = b; b = t; }   // a < b
        u32 old = atomicMin(&L[b], a);
        if (old == b) return;
        b = old;
    }
}

// ========== vote + bitpack (pure streaming, full occupancy) ==========
// 2048 blocks x 256 thr; each wave produces 8 words. Also zeroes global hash.
__global__ __launch_bounds__(256) void vote_pack_kernel(const float* __restrict__ x,
                                                        u64* __restrict__ mp0,
                                                        u32* __restrict__ hkeys,
                                                        u32* __restrict__ hvals) {
    int t = threadIdx.x, lane = t & 63;
    { int idx = blockIdx.x * 256 + t;
      if (idx < GHASH) hkeys[idx] = 0u;
      else if (idx < 2 * GHASH) hvals[idx - GHASH] = 0u; }

    int wave = blockIdx.x * 4 + (t >> 6);            // 8192 waves
    for (int k = 0; k < 8; ++k) {
        int word = wave + k * 8192;                  // < NWORDS
        int img = word >> 12;
        size_t p = (size_t)(word & 4095) * 64 + lane;
        const float* xb = x + (size_t)img * 4 * IMG;
        bool p1 = xb[p + (size_t)IMG]     > 0.5f;
        bool p2 = xb[p + 2 * (size_t)IMG] > 0.5f;
        bool p3 = xb[p + 3 * (size_t)IMG] > 0.5f;
        u64 bits = __ballot(p1 | (p2 & p3));
        if (lane == 0) mp0[word] = bits;
    }
}

// ========== morph (4 passes, double-buffered) + band CCL ==========
// 16 img x 64 bands of 8 rows = 1024 blocks x 256 thr. Packed input (L2).
__global__ __launch_bounds__(256) void morph_ccl_kernel(const u64* __restrict__ mp0,
                                                        u64* __restrict__ mp,
                                                        u32* __restrict__ L) {
    __shared__ u64 Ma[BWORDS], Mb[BWORDS];
    __shared__ u32 Ll[NODES];
    int blk = blockIdx.x;
    int img = blk >> 6;
    int r0  = (blk & 63) * BAND;
    int t = threadIdx.x;
    int rr = r0 - HALO + (t >> 3);

    if (t < BWORDS)
        Ma[t] = (rr >= 0 && rr < Hh) ? mp0[(size_t)img * WPI + (size_t)rr * WROW + (t & 7)] : 0;
    // init CCL labels while loaders work
    for (int i = t; i < NODES; i += 256) Ll[i] = (u32)i;
    __syncthreads();

    // close: dilate, erode; open: erode, dilate  (A->B->A->B->A)
    if (t < BWORDS) Mb[t] = morph_word(Ma, t, rr, false);
    __syncthreads();
    if (t < BWORDS) Ma[t] = morph_word(Mb, t, rr, true);
    __syncthreads();
    if (t < BWORDS) Mb[t] = morph_word(Ma, t, rr, true);
    __syncthreads();
    if (t < BWORDS) Ma[t] = morph_word(Mb, t, rr, false);
    __syncthreads();

    // owned rows: Ma[HALO*8 .. HALO*8+63]
    if (t < BAND * WROW)
        mp[(size_t)img * WPI + (size_t)r0 * WROW + t] = Ma[HALO * WROW + t];

    // ---- band CCL: nodes = within-word run starts ----
    // unions: 56 vertical (7 row-pairs x 8 words) + 56 horizontal (8 rows x 7)
    if (t < 56) {
        int rp = t >> 3, w = t & 7;                  // rows (rp, rp+1)
        u64 a = Ma[HALO * WROW + rp * 8 + w], b = Ma[HALO * WROW + (rp + 1) * 8 + w];
        u64 ov = a & b, seg = ov & ~(ov << 1);
        while (seg) {
            int s = __ffsll(seg) - 1; seg &= seg - 1;
            uf_merge((u32*)Ll, (u32)(rp * Ww + w * 64) + runstart(a, s),
                               (u32)((rp + 1) * Ww + w * 64) + runstart(b, s));
        }
    } else if (t >= 64 && t < 120) {
        int ht = t - 64;
        int r = ht / 7, w = 1 + ht % 7;              // rows 0..7, word pairs (w-1,w)
        u64 a = Ma[HALO * WROW + r * 8 + w - 1], b = Ma[HALO * WROW + r * 8 + w];
        if ((a >> 63) & b & 1ULL)
            uf_merge((u32*)Ll, (u32)(r * Ww + (w - 1) * 64) + runstart(a, 63),
                               (u32)(r * Ww + w * 64));
    }
    __syncthreads();

    // flatten per run + write global L (64 word tasks)
    u32 pbase = (u32)img * IMG + (u32)r0 * Ww;    // node n -> pixel pbase+n
    if (t < 64) {
        u64 bits = Ma[HALO * WROW + t];
        u32 nb = (u32)(t >> 3) * Ww + (u32)(t & 7) * 64;
        u64 st = bits & ~(bits << 1);
        while (st) {
            int s = __ffsll(st) - 1; st &= st - 1;
            u32 n = nb + (u32)s;
            u32 r = n, p = Ll[r];
            while (p != r) { r = p; p = Ll[r]; }   // read-only chase
            L[pbase + n] = pbase + r;
        }
    }
}

// ========== cross-band boundary merges ==========
#define BITEMS (BATCH * 63 * WROW)    // 8064
__global__ void border_merge_kernel(const u64* __restrict__ mp, u32* L) {
    int e = blockIdx.x * blockDim.x + threadIdx.x;
    if (e >= BITEMS) return;
    int w = e & 7, k = (e >> 3) % 63 + 1, img = e / (63 * 8);
    int R = k * BAND;                  // boundary rows R-1, R
    const u64* ib = mp + (size_t)img * WPI;
    u64 a = ib[(size_t)(R - 1) * WROW + w];
    u64 b = ib[(size_t)R * WROW + w];
    u64 ov = a & b, seg = ov & ~(ov << 1);
    u32 ga = (u32)img * IMG + (u32)(R - 1) * Ww + (u32)(w * 64);
    while (seg) {
        int s = __ffsll(seg) - 1; seg &= seg - 1;
        uf_merge(L, ga + runstart(a, s), ga + (u32)Ww + runstart(b, s));
    }
}

// ========== count: wave-aggregated run accumulation ==========
// One LDS-hash add per DISTINCT ROOT per wave (butterfly-summed), instead of
// one per run -> kills same-address LDS atomic serialization on giant comps.
__global__ __launch_bounds__(256) void count_kernel(const u64* __restrict__ mp,
                                                    u32* __restrict__ L,
                                                    u32* __restrict__ hkeys,
                                                    u32* __restrict__ hvals) {
    __shared__ u32 keys[LHASH];
    __shared__ u32 vals[LHASH];
    int tid = threadIdx.x;
    for (int i = tid; i < LHASH; i += 256) { keys[i] = 0xFFFFFFFFu; vals[i] = 0u; }
    __syncthreads();

    int widx = blockIdx.x * 256 + tid;        // exact grid: NWORDS threads
    u64 bits = mp[widx];
    u32 gbase = (u32)widx * 64;
    u64 st = bits & ~(bits << 1);

    u32 r = 0, len = 0;
    bool pending = false;
    if (st) {                                  // load + resolve first run
        int s = __ffsll(st) - 1; st &= st - 1;
        u32 node = gbase + (u32)s;
        u32 rr = node, p = L[rr];
        while (p != rr) { rr = p; p = L[rr]; }
        L[node] = rr;                          // own-slot compress for final
        r = rr; len = runlen(bits, s); pending = true;
    }
    while (true) {
        u64 act = __ballot(pending);
        if (!act) break;
        int leader = __ffsll(act) - 1;
        u32 lr = __shfl(r, leader);
        bool mine = pending && (r == lr);
        u32 c = mine ? len : 0u;
        c += __shfl_xor(c, 32); c += __shfl_xor(c, 16); c += __shfl_xor(c, 8);
        c += __shfl_xor(c, 4);  c += __shfl_xor(c, 2);  c += __shfl_xor(c, 1);
        if ((tid & 63) == leader) {
            u32 h = (lr * 2654435761u) & (LHASH - 1);
            while (true) {
                u32 k = atomicCAS(&keys[h], 0xFFFFFFFFu, lr);
                if (k == 0xFFFFFFFFu || k == lr) { atomicAdd(&vals[h], c); break; }
                h = (h + 1) & (LHASH - 1);
            }
        }
        if (mine) {                            // advance to next run
            if (st) {
                int s = __ffsll(st) - 1; st &= st - 1;
                u32 node = gbase + (u32)s;
                u32 rr = node, p = L[rr];
                while (p != rr) { rr = p; p = L[rr]; }
                L[node] = rr;
                r = rr; len = runlen(bits, s);
            } else pending = false;
        }
    }
    __syncthreads();
    for (int i = tid; i < LHASH; i += 256) {
        u32 k = keys[i];
        if (k != 0xFFFFFFFFu) {
            u32 h = (k * 2654435761u) & (GHASH - 1);
            while (true) {
                u32 kk = atomicCAS(&hkeys[h], 0u, k + 1u);
                if (kk == 0u || kk == k + 1u) { atomicAdd(&hvals[h], vals[i]); break; }
                h = (h + 1) & (GHASH - 1);
            }
        }
    }
}

// ========== final: keep-mask per word, coalesced float4 writes ==========
__global__ __launch_bounds__(256) void final_kernel(const u64* __restrict__ mp,
                                                    const u32* __restrict__ L,
                                                    const u32* __restrict__ hkeys,
                                                    const u32* __restrict__ hvals,
                                                    float* __restrict__ out) {
    __shared__ u64 km[256];
    int tid = threadIdx.x;
    int widx = blockIdx.x * 256 + tid;
    u64 bits = mp[widx];
    u32 gbase = (u32)widx * 64;
    u64 keep = 0;
    u64 st = bits & ~(bits << 1);
    while (st) {
        int s = __ffsll(st) - 1; st &= st - 1;
        u32 r = L[gbase + (u32)s];           // exact root (count compressed)
        u32 h = (r * 2654435761u) & (GHASH - 1);
        u32 szv = 0;
        while (true) {
            u32 k = hkeys[h];
            if (k == r + 1u) { szv = hvals[h]; break; }
            if (k == 0u) break;
            h = (h + 1) & (GHASH - 1);
        }
        if (szv > MIN_SIZE) {
            u32 len = runlen(bits, s);
            keep |= (len == 64 ? ~0ULL : ((1ULL << len) - 1ULL)) << s;
        }
    }
    km[tid] = keep;
    __syncthreads();
    float4* o4 = (float4*)out + (size_t)blockIdx.x * 4096;
    for (int i = tid; i < 4096; i += 256) {
        u32 nib = (u32)(km[i >> 4] >> ((i & 15) * 4)) & 0xFu;
        o4[i] = make_float4(nib & 1u ? 1.f : 0.f, nib & 2u ? 1.f : 0.f,
                            nib & 4u ? 1.f : 0.f, nib & 8u ? 1.f : 0.f);
    }
}

extern "C" void kernel_launch(void* const* d_in, const int* in_sizes, int n_in,
                              void* d_out, int out_size, void* d_ws, size_t ws_size,
                              hipStream_t stream) {
    const float* x = (const float*)d_in[0];
    float* out = (float*)d_out;

    // ws: mp0 512KB | mp 512KB | L 16MB | hkeys 512KB | hvals 512KB  (~18MB)
    u64* mp0 = (u64*)d_ws;
    u64* mp  = mp0 + NWORDS;
    u32* L   = (u32*)(mp + NWORDS);
    u32* hkeys = L + TOT;
    u32* hvals = hkeys + GHASH;

    const int block = 256;

    vote_pack_kernel<<<2048, block, 0, stream>>>(x, mp0, hkeys, hvals);
    morph_ccl_kernel<<<BATCH * 64, block, 0, stream>>>(mp0, mp, L);
    border_merge_kernel<<<(BITEMS + block - 1) / block, block, 0, stream>>>(mp, L);
    count_kernel<<<NWORDS / block, block, 0, stream>>>(mp, L, hkeys, hvals);
    final_kernel<<<NWORDS / block, block, 0, stream>>>(mp, L, hkeys, hvals, out);
}

// Round 12
// 81.770 us; speedup vs baseline: 1.2923x; 1.2923x over previous
//
#include <hip/hip_runtime.h>

typedef unsigned long long u64;
typedef unsigned u32;

#define BATCH 16
#define Hh 512
#define Ww 512
#define IMG (Hh * Ww)          // 262144
#define TOT (BATCH * IMG)      // 4194304
#define WPI 4096               // words per image
#define WROW 8                 // words per row
#define NWORDS (TOT / 64)      // 65536
#define MIN_SIZE 262           // keep strictly greater
#define LHASH 2048             // per-block hash in count
#define MAXRUNS (NWORDS * 32)  // hard cap on total runs (2M)

#define BAND 8
#define HALO 4
#define BROWS (BAND + 2 * HALO)     // 16
#define BWORDS (BROWS * WROW)       // 128
#define NODES (BAND * Ww)           // 4096 pixel-nodes per band

// run start within a word: nearest zero at-or-below set bit s, +1.
__device__ __forceinline__ u32 runstart(u64 bits, int s) {
    u64 ms = (s >= 63) ? ~0ULL : ((1ULL << (s + 1)) - 1);
    u64 nz = ~bits & ms;
    return nz ? (u32)(64 - __clzll(nz)) : 0u;
}
__device__ __forceinline__ u32 runlen(u64 bits, int s) {
    u64 v = ~(bits >> s);
    return v ? (u32)(__ffsll(v) - 1) : (u32)(64 - s);
}

__device__ __forceinline__ u64 morph_word(const u64* M, int w, int rr, bool er) {
    const u64 B = er ? ~0ULL : 0ULL;
    int wx = w & 7;
    u64 cc = M[w];
    u64 lf = (cc << 1) | (wx > 0 ? (M[w - 1] >> 63) : (er ? 1ULL : 0ULL));
    u64 rt = (cc >> 1) | (wx < 7 ? (M[w + 1] << 63) : (er ? (1ULL << 63) : 0ULL));
    u64 up = (rr <= 0)      ? B : (w >= WROW          ? M[w - WROW] : B);
    u64 dn = (rr >= Hh - 1) ? B : (w < BWORDS - WROW  ? M[w + WROW] : B);
    return er ? (cc & lf & rt & up & dn) : (cc | lf | rt | up | dn);
}

// ---------------- union-find primitives (LDS or global) ----------------
template <typename P>
__device__ __forceinline__ u32 uf_find_halve(P L, u32 x) {
    while (true) {
        u32 p = L[x];
        if (p == x) return x;
        u32 gp = L[p];
        if (gp == p) return p;
        atomicMin(&L[x], gp);   // halving: gp <= p < x, monotone-safe
        x = gp;
    }
}
template <typename P>
__device__ __forceinline__ void uf_merge(P L, u32 a, u32 b) {
    while (true) {
        a = uf_find_halve(L, a);
        b = uf_find_halve(L, b);
        if (a == b) return;
        if (a > b) { u32 t = a; a = b; b = t; }   // a < b
        u32 old = atomicMin(&L[b], a);
        if (old == b) return;
        b = old;
    }
}

// ========== vote + bitpack, float4-vectorized ==========
// 1024 blocks x 256 thr; thread handles 16 px via 12 float4 loads (192 B),
// packs u16 -> u64 via two shfl_xor steps. Block = 4096 px (64 words).
__global__ __launch_bounds__(256) void vote_pack_kernel(const float4* __restrict__ x4,
                                                        u64* __restrict__ mp0,
                                                        u32* __restrict__ runCtr) {
    int t = threadIdx.x, blk = blockIdx.x;
    if (blk == 0 && t == 0) *runCtr = 0u;
    int img = blk >> 6;                          // 64 blocks per image
    size_t p4 = (size_t)((blk & 63) * 4096 + t * 16) >> 2;  // float4 idx in channel
    const float4* c1 = x4 + ((size_t)img * 4 + 1) * (IMG / 4);
    const float4* c2 = x4 + ((size_t)img * 4 + 2) * (IMG / 4);
    const float4* c3 = x4 + ((size_t)img * 4 + 3) * (IMG / 4);
    u32 m = 0;
    #pragma unroll
    for (int q = 0; q < 4; ++q) {
        float4 a1 = c1[p4 + q], a2 = c2[p4 + q], a3 = c3[p4 + q];
        u32 b0 = (a1.x > 0.5f) | ((a2.x > 0.5f) & (a3.x > 0.5f));
        u32 b1 = (a1.y > 0.5f) | ((a2.y > 0.5f) & (a3.y > 0.5f));
        u32 b2 = (a1.z > 0.5f) | ((a2.z > 0.5f) & (a3.z > 0.5f));
        u32 b3 = (a1.w > 0.5f) | ((a2.w > 0.5f) & (a3.w > 0.5f));
        m |= (b0 | (b1 << 1) | (b2 << 2) | (b3 << 3)) << (q * 4);
    }
    u32 w32 = m | (__shfl_xor(m, 1) << 16);                 // lanes even: px..+31
    u64 w = (u64)w32 | ((u64)__shfl_xor(w32, 2) << 32);     // lanes %4==0: full word
    if ((t & 3) == 0) mp0[(size_t)blk * 64 + (t >> 2)] = w;
}

// ========== morph (4 passes) + band CCL with COMPACT RUN IDS ==========
// 1024 blocks (16 img x 64 bands of 8 rows). Assigns compact ids to runs,
// writes wordbase[], zeroes counts[base..base+n), writes L[id]=band-root-id.
__global__ __launch_bounds__(256) void morph_ccl_kernel(const u64* __restrict__ mp0,
                                                        u64* __restrict__ mp,
                                                        u32* __restrict__ L,
                                                        u32* __restrict__ wordbase,
                                                        u32* __restrict__ counts,
                                                        u32* __restrict__ runCtr) {
    __shared__ u64 Ma[BWORDS], Mb[BWORDS];
    __shared__ u32 Ll[NODES];
    __shared__ u32 wb_l[64];
    __shared__ u32 baseSh, totSh;
    int blk = blockIdx.x;
    int img = blk >> 6;
    int r0  = (blk & 63) * BAND;
    int t = threadIdx.x;
    int rr = r0 - HALO + (t >> 3);

    if (t < BWORDS)
        Ma[t] = (rr >= 0 && rr < Hh) ? mp0[(size_t)img * WPI + (size_t)rr * WROW + (t & 7)] : 0;
    for (int i = t; i < NODES; i += 256) Ll[i] = (u32)i;
    __syncthreads();

    // close: D,E ; open: E,D
    if (t < BWORDS) Mb[t] = morph_word(Ma, t, rr, false);
    __syncthreads();
    if (t < BWORDS) Ma[t] = morph_word(Mb, t, rr, true);
    __syncthreads();
    if (t < BWORDS) Mb[t] = morph_word(Ma, t, rr, true);
    __syncthreads();
    if (t < BWORDS) Ma[t] = morph_word(Mb, t, rr, false);
    __syncthreads();

    if (t < 64)
        mp[(size_t)img * WPI + (size_t)r0 * WROW + t] = Ma[32 + t];

    // ---- run count + exclusive scan (wave 0) + global base ----
    u32 myexcl = 0;
    if (t < 64) {
        u64 bits = Ma[32 + t];
        u64 st = bits & ~(bits << 1);
        u32 cnt = __popcll(st);
        u32 inc = cnt;
        #pragma unroll
        for (int d = 1; d < 64; d <<= 1) {
            u32 v = __shfl_up(inc, d);
            if (t >= d) inc += v;
        }
        myexcl = inc - cnt;
        if (t == 63) { baseSh = atomicAdd(runCtr, inc); totSh = inc; }
    }
    __syncthreads();
    u32 base = baseSh, tot = totSh;
    if (t < 64) {
        wb_l[t] = base + myexcl;
        wordbase[(size_t)img * WPI + (size_t)r0 * WROW + t] = base + myexcl;
    }
    for (u32 i = t; i < tot; i += 256) counts[base + i] = 0u;   // exact zeroing
    __syncthreads();

    // ---- band CCL unions on pixel-nodes (as R11, proven) ----
    if (t < 56) {
        int rp = t >> 3, w = t & 7;
        u64 a = Ma[32 + rp * 8 + w], b = Ma[32 + (rp + 1) * 8 + w];
        u64 ov = a & b, seg = ov & ~(ov << 1);
        while (seg) {
            int s = __ffsll(seg) - 1; seg &= seg - 1;
            uf_merge((u32*)Ll, (u32)(rp * Ww + w * 64) + runstart(a, s),
                               (u32)((rp + 1) * Ww + w * 64) + runstart(b, s));
        }
    } else if (t >= 64 && t < 120) {
        int ht = t - 64;
        int r = ht / 7, w = 1 + ht % 7;
        u64 a = Ma[32 + r * 8 + w - 1], b = Ma[32 + r * 8 + w];
        if ((a >> 63) & b & 1ULL)
            uf_merge((u32*)Ll, (u32)(r * Ww + (w - 1) * 64) + runstart(a, 63),
                               (u32)(r * Ww + w * 64));
    }
    __syncthreads();

    // ---- flatten + write L[compact id] = compact root id ----
    if (t < 64) {
        u64 bits = Ma[32 + t];
        u64 st = bits & ~(bits << 1);
        u32 myid = wb_l[t];
        while (st) {
            int s = __ffsll(st) - 1; st &= st - 1;
            u32 n = (u32)(t >> 3) * Ww + (u32)(t & 7) * 64 + (u32)s;
            u32 r = n, p = Ll[r];
            while (p != r) { r = p; p = Ll[r]; }       // read-only LDS chase
            u32 rrow = r >> 9, rcol = r & 511;
            u32 rw = rrow * 8 + (rcol >> 6);           // owned word of root
            u64 rbits = Ma[32 + rw];
            u64 rst = rbits & ~(rbits << 1);
            u32 rid = wb_l[rw] + (u32)__popcll(rst & (((u64)1 << (rcol & 63)) - 1));
            L[myid++] = rid;                            // rank order == id order
        }
    }
}

// ========== cross-band boundary merges (compact ids) ==========
#define BITEMS (BATCH * 63 * WROW)    // 8064
__global__ void border_merge_kernel(const u64* __restrict__ mp,
                                    const u32* __restrict__ wordbase, u32* L) {
    int e = blockIdx.x * blockDim.x + threadIdx.x;
    if (e >= BITEMS) return;
    int w = e & 7, k = (e >> 3) % 63 + 1, img = e / (63 * 8);
    int R = k * BAND;                  // boundary rows R-1, R
    size_t wa_i = (size_t)img * WPI + (size_t)(R - 1) * WROW + w;
    size_t wb_i = (size_t)img * WPI + (size_t)R * WROW + w;
    u64 a = mp[wa_i], b = mp[wb_i];
    u64 ov = a & b, seg = ov & ~(ov << 1);
    if (!seg) return;
    u64 sta = a & ~(a << 1), stb = b & ~(b << 1);
    u32 wba = wordbase[wa_i], wbb = wordbase[wb_i];
    while (seg) {
        int s = __ffsll(seg) - 1; seg &= seg - 1;
        u32 ra = runstart(a, s), rb = runstart(b, s);
        u32 ida = wba + (u32)__popcll(sta & (((u64)1 << ra) - 1));
        u32 idb = wbb + (u32)__popcll(stb & (((u64)1 << rb) - 1));
        uf_merge(L, ida, idb);
    }
}

// ========== count: wave-aggregated, direct counts array ==========
__global__ __launch_bounds__(256) void count_kernel(const u64* __restrict__ mp,
                                                    const u32* __restrict__ wordbase,
                                                    u32* __restrict__ L,
                                                    u32* __restrict__ counts) {
    __shared__ u32 keys[LHASH];
    __shared__ u32 vals[LHASH];
    int tid = threadIdx.x;
    for (int i = tid; i < LHASH; i += 256) { keys[i] = 0xFFFFFFFFu; vals[i] = 0u; }
    __syncthreads();

    int widx = blockIdx.x * 256 + tid;        // exact grid: NWORDS threads
    u64 bits = mp[widx];
    u64 st = bits & ~(bits << 1);
    u32 id = wordbase[widx];

    u32 r = 0, len = 0;
    bool pending = false;
    if (st) {
        int s = __ffsll(st) - 1; st &= st - 1;
        u32 rr = id, p = L[rr];
        while (p != rr) { rr = p; p = L[rr]; }
        L[id] = rr;                            // own-slot compress
        r = rr; len = runlen(bits, s); id++; pending = true;
    }
    while (true) {
        u64 act = __ballot(pending);
        if (!act) break;
        int leader = __ffsll(act) - 1;
        u32 lr = __shfl(r, leader);
        bool mine = pending && (r == lr);
        u32 c = mine ? len : 0u;
        c += __shfl_xor(c, 32); c += __shfl_xor(c, 16); c += __shfl_xor(c, 8);
        c += __shfl_xor(c, 4);  c += __shfl_xor(c, 2);  c += __shfl_xor(c, 1);
        if ((tid & 63) == leader) {
            u32 h = (lr * 2654435761u) & (LHASH - 1);
            while (true) {
                u32 k = atomicCAS(&keys[h], 0xFFFFFFFFu, lr);
                if (k == 0xFFFFFFFFu || k == lr) { atomicAdd(&vals[h], c); break; }
                h = (h + 1) & (LHASH - 1);
            }
        }
        if (mine) {
            if (st) {
                int s = __ffsll(st) - 1; st &= st - 1;
                u32 rr = id, p = L[rr];
                while (p != rr) { rr = p; p = L[rr]; }
                L[id] = rr;
                r = rr; len = runlen(bits, s); id++;
            } else pending = false;
        }
    }
    __syncthreads();
    for (int i = tid; i < LHASH; i += 256)
        if (keys[i] != 0xFFFFFFFFu) atomicAdd(&counts[keys[i]], vals[i]);
}

// ========== final: keep-mask per word, coalesced float4 writes ==========
__global__ __launch_bounds__(256) void final_kernel(const u64* __restrict__ mp,
                                                    const u32* __restrict__ wordbase,
                                                    const u32* __restrict__ L,
                                                    const u32* __restrict__ counts,
                                                    float* __restrict__ out) {
    __shared__ u64 km[256];
    int tid = threadIdx.x;
    int widx = blockIdx.x * 256 + tid;
    u64 bits = mp[widx];
    u64 st = bits & ~(bits << 1);
    u32 id = wordbase[widx];
    u64 keep = 0;
    while (st) {
        int s = __ffsll(st) - 1; st &= st - 1;
        u32 r = L[id++];                      // exact root (count compressed)
        if (counts[r] > MIN_SIZE) {
            u32 len = runlen(bits, s);
            keep |= (len == 64 ? ~0ULL : ((1ULL << len) - 1ULL)) << s;
        }
    }
    km[tid] = keep;
    __syncthreads();
    float4* o4 = (float4*)out + (size_t)blockIdx.x * 4096;
    for (int i = tid; i < 4096; i += 256) {
        u32 nib = (u32)(km[i >> 4] >> ((i & 15) * 4)) & 0xFu;
        o4[i] = make_float4(nib & 1u ? 1.f : 0.f, nib & 2u ? 1.f : 0.f,
                            nib & 4u ? 1.f : 0.f, nib & 8u ? 1.f : 0.f);
    }
}

extern "C" void kernel_launch(void* const* d_in, const int* in_sizes, int n_in,
                              void* d_out, int out_size, void* d_ws, size_t ws_size,
                              hipStream_t stream) {
    const float* x = (const float*)d_in[0];
    float* out = (float*)d_out;

    // ws: mp0 512KB | mp 512KB | wordbase 256KB | L 8MB | counts 8MB | runCtr
    u64* mp0 = (u64*)d_ws;
    u64* mp  = mp0 + NWORDS;
    u32* wordbase = (u32*)(mp + NWORDS);
    u32* L      = wordbase + NWORDS;
    u32* counts = L + MAXRUNS;
    u32* runCtr = counts + MAXRUNS;

    const int block = 256;

    vote_pack_kernel<<<1024, block, 0, stream>>>((const float4*)x, mp0, runCtr);
    morph_ccl_kernel<<<BATCH * 64, block, 0, stream>>>(mp0, mp, L, wordbase, counts, runCtr);
    border_merge_kernel<<<(BITEMS + block - 1) / block, block, 0, stream>>>(mp, wordbase, L);
    count_kernel<<<NWORDS / block, block, 0, stream>>>(mp, wordbase, L, counts);
    final_kernel<<<NWORDS / block, block, 0, stream>>>(mp, wordbase, L, counts, out);
}

// Round 13
// 78.877 us; speedup vs baseline: 1.3397x; 1.0367x over previous
//
#include <hip/hip_runtime.h>

typedef unsigned long long u64;
typedef unsigned u32;
typedef unsigned char u8;

#define BATCH 16
#define Hh 512
#define Ww 512
#define IMG (Hh * Ww)          // 262144
#define TOT (BATCH * IMG)      // 4194304
#define WPI 4096               // words per image
#define WROW 8                 // words per row
#define NWORDS (TOT / 64)      // 65536
#define MIN_SIZE 262           // keep strictly greater
#define MAXRUNS (NWORDS * 32)  // hard cap on total runs (2M)

#define BAND 8
#define HALO 4
#define BROWS (BAND + 2 * HALO)     // 16
#define BWORDS (BROWS * WROW)       // 128
#define NODES (BAND * Ww)           // 4096 pixel-nodes per band

// run start within a word: nearest zero at-or-below set bit s, +1.
__device__ __forceinline__ u32 runstart(u64 bits, int s) {
    u64 ms = (s >= 63) ? ~0ULL : ((1ULL << (s + 1)) - 1);
    u64 nz = ~bits & ms;
    return nz ? (u32)(64 - __clzll(nz)) : 0u;
}
__device__ __forceinline__ u32 runlen(u64 bits, int s) {
    u64 v = ~(bits >> s);
    return v ? (u32)(__ffsll(v) - 1) : (u32)(64 - s);
}

__device__ __forceinline__ u64 morph_word(const u64* M, int w, int rr, bool er) {
    const u64 B = er ? ~0ULL : 0ULL;
    int wx = w & 7;
    u64 cc = M[w];
    u64 lf = (cc << 1) | (wx > 0 ? (M[w - 1] >> 63) : (er ? 1ULL : 0ULL));
    u64 rt = (cc >> 1) | (wx < 7 ? (M[w + 1] << 63) : (er ? (1ULL << 63) : 0ULL));
    u64 up = (rr <= 0)      ? B : (w >= WROW          ? M[w - WROW] : B);
    u64 dn = (rr >= Hh - 1) ? B : (w < BWORDS - WROW  ? M[w + WROW] : B);
    return er ? (cc & lf & rt & up & dn) : (cc | lf | rt | up | dn);
}

// ---------------- union-find primitives (LDS or global) ----------------
template <typename P>
__device__ __forceinline__ u32 uf_find_halve(P L, u32 x) {
    while (true) {
        u32 p = L[x];
        if (p == x) return x;
        u32 gp = L[p];
        if (gp == p) return p;
        atomicMin(&L[x], gp);   // halving: gp <= p < x, monotone-safe
        x = gp;
    }
}
template <typename P>
__device__ __forceinline__ void uf_merge(P L, u32 a, u32 b) {
    while (true) {
        a = uf_find_halve(L, a);
        b = uf_find_halve(L, b);
        if (a == b) return;
        if (a > b) { u32 t = a; a = b; b = t; }   // a < b
        u32 old = atomicMin(&L[b], a);
        if (old == b) return;
        b = old;
    }
}

// ========== vote + bitpack, float4-vectorized ==========
__global__ __launch_bounds__(256) void vote_pack_kernel(const float4* __restrict__ x4,
                                                        u64* __restrict__ mp0,
                                                        u32* __restrict__ runCtr) {
    int t = threadIdx.x, blk = blockIdx.x;
    if (blk == 0 && t == 0) *runCtr = 0u;
    int img = blk >> 6;                          // 64 blocks per image
    size_t p4 = (size_t)((blk & 63) * 4096 + t * 16) >> 2;  // float4 idx in channel
    const float4* c1 = x4 + ((size_t)img * 4 + 1) * (IMG / 4);
    const float4* c2 = x4 + ((size_t)img * 4 + 2) * (IMG / 4);
    const float4* c3 = x4 + ((size_t)img * 4 + 3) * (IMG / 4);
    u32 m = 0;
    #pragma unroll
    for (int q = 0; q < 4; ++q) {
        float4 a1 = c1[p4 + q], a2 = c2[p4 + q], a3 = c3[p4 + q];
        u32 b0 = (a1.x > 0.5f) | ((a2.x > 0.5f) & (a3.x > 0.5f));
        u32 b1 = (a1.y > 0.5f) | ((a2.y > 0.5f) & (a3.y > 0.5f));
        u32 b2 = (a1.z > 0.5f) | ((a2.z > 0.5f) & (a3.z > 0.5f));
        u32 b3 = (a1.w > 0.5f) | ((a2.w > 0.5f) & (a3.w > 0.5f));
        m |= (b0 | (b1 << 1) | (b2 << 2) | (b3 << 3)) << (q * 4);
    }
    u32 w32 = m | (__shfl_xor(m, 1) << 16);                 // lanes even: px..+31
    u64 w = (u64)w32 | ((u64)__shfl_xor(w32, 2) << 32);     // lanes %4==0: full word
    if ((t & 3) == 0) mp0[(size_t)blk * 64 + (t >> 2)] = w;
}

// ========== morph (4 passes) + band CCL with COMPACT RUN IDS ==========
// Writes per-run: L[id] = band-root id, len8[id] = run length, counts[id] = 0.
__global__ __launch_bounds__(256) void morph_ccl_kernel(const u64* __restrict__ mp0,
                                                        u64* __restrict__ mp,
                                                        u32* __restrict__ L,
                                                        u32* __restrict__ wordbase,
                                                        u32* __restrict__ counts,
                                                        u8*  __restrict__ len8,
                                                        u32* __restrict__ runCtr) {
    __shared__ u64 Ma[BWORDS], Mb[BWORDS];
    __shared__ u32 Ll[NODES];
    __shared__ u32 wb_l[64];
    __shared__ u32 baseSh, totSh;
    int blk = blockIdx.x;
    int img = blk >> 6;
    int r0  = (blk & 63) * BAND;
    int t = threadIdx.x;
    int rr = r0 - HALO + (t >> 3);

    if (t < BWORDS)
        Ma[t] = (rr >= 0 && rr < Hh) ? mp0[(size_t)img * WPI + (size_t)rr * WROW + (t & 7)] : 0;
    for (int i = t; i < NODES; i += 256) Ll[i] = (u32)i;
    __syncthreads();

    // close: D,E ; open: E,D
    if (t < BWORDS) Mb[t] = morph_word(Ma, t, rr, false);
    __syncthreads();
    if (t < BWORDS) Ma[t] = morph_word(Mb, t, rr, true);
    __syncthreads();
    if (t < BWORDS) Mb[t] = morph_word(Ma, t, rr, true);
    __syncthreads();
    if (t < BWORDS) Ma[t] = morph_word(Mb, t, rr, false);
    __syncthreads();

    if (t < 64)
        mp[(size_t)img * WPI + (size_t)r0 * WROW + t] = Ma[32 + t];

    // ---- run count + exclusive scan (wave 0) + global base ----
    u32 myexcl = 0;
    if (t < 64) {
        u64 bits = Ma[32 + t];
        u64 st = bits & ~(bits << 1);
        u32 cnt = __popcll(st);
        u32 inc = cnt;
        #pragma unroll
        for (int d = 1; d < 64; d <<= 1) {
            u32 v = __shfl_up(inc, d);
            if (t >= d) inc += v;
        }
        myexcl = inc - cnt;
        if (t == 63) { baseSh = atomicAdd(runCtr, inc); totSh = inc; }
    }
    __syncthreads();
    u32 base = baseSh, tot = totSh;
    if (t < 64) {
        wb_l[t] = base + myexcl;
        wordbase[(size_t)img * WPI + (size_t)r0 * WROW + t] = base + myexcl;
    }
    for (u32 i = t; i < tot; i += 256) counts[base + i] = 0u;   // exact zeroing
    __syncthreads();

    // ---- band CCL unions on pixel-nodes ----
    if (t < 56) {
        int rp = t >> 3, w = t & 7;
        u64 a = Ma[32 + rp * 8 + w], b = Ma[32 + (rp + 1) * 8 + w];
        u64 ov = a & b, seg = ov & ~(ov << 1);
        while (seg) {
            int s = __ffsll(seg) - 1; seg &= seg - 1;
            uf_merge((u32*)Ll, (u32)(rp * Ww + w * 64) + runstart(a, s),
                               (u32)((rp + 1) * Ww + w * 64) + runstart(b, s));
        }
    } else if (t >= 64 && t < 120) {
        int ht = t - 64;
        int r = ht / 7, w = 1 + ht % 7;
        u64 a = Ma[32 + r * 8 + w - 1], b = Ma[32 + r * 8 + w];
        if ((a >> 63) & b & 1ULL)
            uf_merge((u32*)Ll, (u32)(r * Ww + (w - 1) * 64) + runstart(a, 63),
                               (u32)(r * Ww + w * 64));
    }
    __syncthreads();

    // ---- flatten + write L[id] = band-root id, len8[id] ----
    if (t < 64) {
        u64 bits = Ma[32 + t];
        u64 st = bits & ~(bits << 1);
        u32 myid = wb_l[t];
        while (st) {
            int s = __ffsll(st) - 1; st &= st - 1;
            u32 n = (u32)(t >> 3) * Ww + (u32)(t & 7) * 64 + (u32)s;
            u32 r = n, p = Ll[r];
            while (p != r) { r = p; p = Ll[r]; }       // read-only LDS chase
            u32 rrow = r >> 9, rcol = r & 511;
            u32 rw = rrow * 8 + (rcol >> 6);           // owned word of root
            u64 rbits = Ma[32 + rw];
            u64 rst = rbits & ~(rbits << 1);
            u32 rid = wb_l[rw] + (u32)__popcll(rst & (((u64)1 << (rcol & 63)) - 1));
            L[myid] = rid;
            len8[myid] = (u8)runlen(bits, s);          // 1..64 fits u8
            myid++;
        }
    }
}

// ========== cross-band boundary merges (compact ids) ==========
#define BITEMS (BATCH * 63 * WROW)    // 8064
__global__ void border_merge_kernel(const u64* __restrict__ mp,
                                    const u32* __restrict__ wordbase, u32* L) {
    int e = blockIdx.x * blockDim.x + threadIdx.x;
    if (e >= BITEMS) return;
    int w = e & 7, k = (e >> 3) % 63 + 1, img = e / (63 * 8);
    int R = k * BAND;                  // boundary rows R-1, R
    size_t wa_i = (size_t)img * WPI + (size_t)(R - 1) * WROW + w;
    size_t wb_i = (size_t)img * WPI + (size_t)R * WROW + w;
    u64 a = mp[wa_i], b = mp[wb_i];
    u64 ov = a & b, seg = ov & ~(ov << 1);
    if (!seg) return;
    u64 sta = a & ~(a << 1), stb = b & ~(b << 1);
    u32 wba = wordbase[wa_i], wbb = wordbase[wb_i];
    while (seg) {
        int s = __ffsll(seg) - 1; seg &= seg - 1;
        u32 ra = runstart(a, s), rb = runstart(b, s);
        u32 ida = wba + (u32)__popcll(sta & (((u64)1 << ra) - 1));
        u32 idb = wbb + (u32)__popcll(stb & (((u64)1 << rb) - 1));
        uf_merge(L, ida, idb);
    }
}

// ========== accum: dense sweep over compact ids, wave-aggregated ==========
#define ACCUM_STRIDE (1024 * 256)
__global__ __launch_bounds__(256) void accum_kernel(u32* __restrict__ L,
                                                    const u8* __restrict__ len8,
                                                    u32* __restrict__ counts,
                                                    const u32* __restrict__ runCtr) {
    u32 n = *runCtr;
    u32 gid = blockIdx.x * 256 + threadIdx.x;
    int tid = threadIdx.x;
    u32 trips = (n + ACCUM_STRIDE - 1) / ACCUM_STRIDE;   // wave-uniform
    for (u32 k = 0; k < trips; ++k) {
        u32 id = gid + k * ACCUM_STRIDE;
        bool valid = id < n;
        u32 r = 0xFFFFFFFFu, len = 0;
        if (valid) {
            r = id; u32 p = L[r];
            while (p != r) { r = p; p = L[r]; }   // short: band-root + border hops
            L[id] = r;                             // own-slot compress for final
            len = len8[id];
        }
        bool pending = true;
        while (true) {
            u64 act = __ballot(pending);
            if (!act) break;
            int leader = __ffsll(act) - 1;
            u32 lr = __shfl(r, leader);
            bool mine = pending && (r == lr);
            u32 c = mine ? len : 0u;
            c += __shfl_xor(c, 32); c += __shfl_xor(c, 16); c += __shfl_xor(c, 8);
            c += __shfl_xor(c, 4);  c += __shfl_xor(c, 2);  c += __shfl_xor(c, 1);
            if ((tid & 63) == leader && lr != 0xFFFFFFFFu) atomicAdd(&counts[lr], c);
            if (mine) pending = false;
        }
    }
}

// ========== final: keep-mask per word, coalesced float4 writes ==========
__global__ __launch_bounds__(256) void final_kernel(const u64* __restrict__ mp,
                                                    const u32* __restrict__ wordbase,
                                                    const u32* __restrict__ L,
                                                    const u32* __restrict__ counts,
                                                    float* __restrict__ out) {
    __shared__ u64 km[256];
    int tid = threadIdx.x;
    int widx = blockIdx.x * 256 + tid;
    u64 bits = mp[widx];
    u64 st = bits & ~(bits << 1);
    u32 id = wordbase[widx];
    u64 keep = 0;
    while (st) {
        int s = __ffsll(st) - 1; st &= st - 1;
        u32 r = L[id++];                      // exact root (accum compressed)
        if (counts[r] > MIN_SIZE) {
            u32 len = runlen(bits, s);
            keep |= (len == 64 ? ~0ULL : ((1ULL << len) - 1ULL)) << s;
        }
    }
    km[tid] = keep;
    __syncthreads();
    float4* o4 = (float4*)out + (size_t)blockIdx.x * 4096;
    for (int i = tid; i < 4096; i += 256) {
        u32 nib = (u32)(km[i >> 4] >> ((i & 15) * 4)) & 0xFu;
        o4[i] = make_float4(nib & 1u ? 1.f : 0.f, nib & 2u ? 1.f : 0.f,
                            nib & 4u ? 1.f : 0.f, nib & 8u ? 1.f : 0.f);
    }
}

extern "C" void kernel_launch(void* const* d_in, const int* in_sizes, int n_in,
                              void* d_out, int out_size, void* d_ws, size_t ws_size,
                              hipStream_t stream) {
    const float* x = (const float*)d_in[0];
    float* out = (float*)d_out;

    // ws: mp0 .5MB | mp .5MB | wordbase .25MB | L 8MB | counts 8MB | len8 2MB | runCtr
    u64* mp0 = (u64*)d_ws;
    u64* mp  = mp0 + NWORDS;
    u32* wordbase = (u32*)(mp + NWORDS);
    u32* L      = wordbase + NWORDS;
    u32* counts = L + MAXRUNS;
    u8*  len8   = (u8*)(counts + MAXRUNS);
    u32* runCtr = (u32*)(len8 + MAXRUNS);

    const int block = 256;

    vote_pack_kernel<<<1024, block, 0, stream>>>((const float4*)x, mp0, runCtr);
    morph_ccl_kernel<<<BATCH * 64, block, 0, stream>>>(mp0, mp, L, wordbase, counts, len8, runCtr);
    border_merge_kernel<<<(BITEMS + block - 1) / block, block, 0, stream>>>(mp, wordbase, L);
    accum_kernel<<<1024, block, 0, stream>>>(L, len8, counts, runCtr);
    final_kernel<<<NWORDS / block, block, 0, stream>>>(mp, wordbase, L, counts, out);
}